// Round 1
// baseline (161.551 us; speedup 1.0000x reference)
//
#include <hip/hip_runtime.h>

// Replicate reference fp32 arithmetic exactly: no FMA contraction in the
// distance math (numpy evaluates (sq_n + sq_m) - 2*dot with plain rounded ops).
#pragma clang fp contract(off)

#define NBATCH 256   // B*L
#define NPTS   512   // points per batch
#define JDIM   128   // logit dim
#define TILE_J 16    // ypred rows staged per LDS tile (16*512*4 = 32 KB)

__global__ __launch_bounds__(512) void fused_loss_kernel(
    const float* __restrict__ ypred,   // [NBATCH, JDIM, NPTS]
    const float* __restrict__ xyz,     // [NBATCH, NPTS, 3]
    float* __restrict__ partials)      // [NBATCH]
{
    __shared__ float4 smem4[2048];           // 32 KB, reused across phases
    float* smemf = (float*)smem4;

    const int bl = blockIdx.x;
    const int n  = threadIdx.x;              // 0..511, one point per thread

    // ---- Phase A setup: stage xyz + squared norms in LDS ----
    {
        const float* xp = xyz + (size_t)bl * NPTS * 3;
        float x = xp[3 * n + 0];
        float y = xp[3 * n + 1];
        float z = xp[3 * n + 2];
        float sq = (x * x + y * y) + z * z;  // matches np.sum(x*x, -1) order
        smem4[n] = make_float4(x, y, z, sq);
    }
    __syncthreads();

    const float4 pn = smem4[n];
    const float xn = pn.x, yn = pn.y, zn = pn.z, sqn = pn.w;

    // ---- Phase A: argmax(dist) and argmin(masked dist), first-occurrence ----
    float bestmax = -1.0f;   int ima = 0;
    float bestmin = 3.0e38f; int imi = 0;

    #pragma unroll 8
    for (int m = 0; m < NPTS; ++m) {
        float4 q = smem4[m];                 // wave-uniform addr -> LDS broadcast
        float p0 = xn * q.x;
        float p1 = yn * q.y;
        float p2 = zn * q.z;
        float dot = (p0 + p1) + p2;          // plain sequential, no fma
        float d2  = (sqn + q.w) - 2.0f * dot;
        d2 = fmaxf(d2, 0.0f);
        float dist = sqrtf(d2);              // IEEE correctly-rounded (hipcc default)
        if (m == n) dist = 0.0f;             // where(eye, 0, dist)

        // argmax: strict > keeps first occurrence of the max
        bool gt = dist > bestmax;
        ima     = gt ? m : ima;
        bestmax = gt ? dist : bestmax;

        // masked argmin: dist==0 -> 1e6 (self + exact dupes), strict <
        float dm = (dist == 0.0f) ? 1.0e6f : dist;
        bool lt  = dm < bestmin;
        imi      = lt ? m : imi;
        bestmin  = lt ? dm : bestmin;
    }
    __syncthreads();   // done with xyz LDS; reuse for ypred tiles

    // ---- Phase B: sim[n][ima] and sim[n][imi] via LDS-staged ypred rows ----
    const float* yp = ypred + (size_t)bl * JDIM * NPTS;
    float accmax = 0.0f, accmin = 0.0f;

    for (int t = 0; t < JDIM / TILE_J; ++t) {
        // stage 16 rows (8192 floats) coalesced, 4 x float4 per thread
        const float4* src = (const float4*)(yp + (size_t)t * TILE_J * NPTS);
        #pragma unroll
        for (int u = 0; u < 4; ++u)
            smem4[u * 512 + n] = src[u * 512 + n];
        __syncthreads();

        #pragma unroll
        for (int r = 0; r < TILE_J; ++r) {
            float a = smemf[r * NPTS + n];    // stride-1: conflict-free
            float b = smemf[r * NPTS + ima];  // gather (random, L DS ~2-way)
            float c = smemf[r * NPTS + imi];
            accmax = fmaf(a, b, accmax);      // order-insensitive (averages out)
            accmin = fmaf(a, c, accmin);
        }
        __syncthreads();
    }

    // ---- block reduction of (sim_at_max - sim_at_min) ----
    float diff = accmax - accmin;
    #pragma unroll
    for (int off = 32; off > 0; off >>= 1)
        diff += __shfl_down(diff, off);       // wave64 reduce

    __shared__ float wsum[8];
    if ((n & 63) == 0) wsum[n >> 6] = diff;
    __syncthreads();
    if (n == 0) {
        float s = 0.0f;
        #pragma unroll
        for (int w = 0; w < 8; ++w) s += wsum[w];
        partials[bl] = s;
    }
}

__global__ __launch_bounds__(256) void reduce_mean_kernel(
    const float* __restrict__ partials, float* __restrict__ out)
{
    float v = partials[threadIdx.x];          // 256 partials, 256 threads
    #pragma unroll
    for (int off = 32; off > 0; off >>= 1)
        v += __shfl_down(v, off);

    __shared__ float w[4];
    if ((threadIdx.x & 63) == 0) w[threadIdx.x >> 6] = v;
    __syncthreads();
    if (threadIdx.x == 0)
        out[0] = (w[0] + w[1] + w[2] + w[3]) * (1.0f / (float)(NBATCH * NPTS));
}

extern "C" void kernel_launch(void* const* d_in, const int* in_sizes, int n_in,
                              void* d_out, int out_size, void* d_ws, size_t ws_size,
                              hipStream_t stream) {
    const float* ypred = (const float*)d_in[0];   // [8,32,128,512] f32
    const float* xyz   = (const float*)d_in[1];   // [8,32,512,3]  f32
    float* partials    = (float*)d_ws;            // 256 floats
    float* out         = (float*)d_out;           // scalar

    fused_loss_kernel<<<NBATCH, 512, 0, stream>>>(ypred, xyz, partials);
    reduce_mean_kernel<<<1, 256, 0, stream>>>(partials, out);
}

// Round 2
// 131.111 us; speedup vs baseline: 1.2322x; 1.2322x over previous
//
#include <hip/hip_runtime.h>

// Keep the reference's exact fp32 arithmetic for d2: no FMA contraction.
// (numpy evaluates (sq_n + sq_m) - 2*dot with plain rounded ops)
#pragma clang fp contract(off)

#define NBATCH 256   // B*L
#define NPTS   512   // points per batch
#define JDIM   128   // logit dim
#define TILE_J 16    // ypred rows per LDS tile (16*512*4 = 32 KB)

// d2-space comparison: sqrt is monotone, so argmax/argmin over dist equal
// argmax/argmin over d2 except when two distinct d2 collapse to the same
// float sqrt (ref then takes the first index). Accepted risk; bench-verified.
__global__ __launch_bounds__(1024) void fused_loss_kernel(
    const float* __restrict__ ypred,   // [NBATCH, JDIM, NPTS]
    const float* __restrict__ xyz,     // [NBATCH, NPTS, 3]
    float* __restrict__ partials)      // [NBATCH]
{
    __shared__ float4 tiles[2048];         // 32 KB: xyz (phase A), ypred tiles (phase B)
    __shared__ float  cmbv[2][2][NPTS];    // 8 KB  [max/min][half][n]
    __shared__ int    cmbi[2][2][NPTS];    // 8 KB
    __shared__ int    pidx[2][NPTS];       // 4 KB  final [ima/imi][n]
    __shared__ float  wred[16];

    const int tid  = threadIdx.x;          // 0..1023
    const int n    = tid & (NPTS - 1);     // point owned by this thread
    const int half = tid >> 9;             // m-range half (phase A), role (phase B)
    const int bl   = blockIdx.x;
    float* smemf = (float*)tiles;

    // ---- stage xyz + squared norms (order matches np.sum(x*x,-1)) ----
    if (tid < NPTS) {
        const float* xp = xyz + (size_t)bl * NPTS * 3;
        float x = xp[3 * tid + 0];
        float y = xp[3 * tid + 1];
        float z = xp[3 * tid + 2];
        float sq = (x * x + y * y) + z * z;
        tiles[tid] = make_float4(x, y, z, sq);
    }
    __syncthreads();

    const float4 pn = tiles[n];

    // ---- Phase A: each thread scans 256 m's (its half) in d2 space ----
    float bmax = -1.0f;   int ima = 0;
    float bmin = 3.0e38f; int imi = 0;
    const int m0 = half * (NPTS / 2);

    #pragma unroll 8
    for (int mm = 0; mm < NPTS / 2; ++mm) {
        int m = m0 + mm;
        float4 q = tiles[m];               // wave-uniform -> LDS broadcast
        float p0 = pn.x * q.x;
        float p1 = pn.y * q.y;
        float p2 = pn.z * q.z;
        float dot = (p0 + p1) + p2;        // same rounding as sq -> self d2 == 0
        float d2  = (pn.w + q.w) - 2.0f * dot;
        d2 = fmaxf(d2, 0.0f);

        bool gt = d2 > bmax;               // strict -> first occurrence
        ima  = gt ? m : ima;
        bmax = gt ? d2 : bmax;

        float dm = (d2 == 0.0f) ? 1.0e6f : d2;  // mask self + exact dupes
        bool lt = dm < bmin;
        imi  = lt ? m : imi;
        bmin = lt ? dm : bmin;
    }

    cmbv[0][half][n] = bmax;  cmbi[0][half][n] = ima;
    cmbv[1][half][n] = bmin;  cmbi[1][half][n] = imi;
    __syncthreads();

    // merge halves; strict compare keeps the earlier half on exact ties
    if (half == 0) {
        float v0 = cmbv[0][0][n], v1 = cmbv[0][1][n];
        int   i0 = cmbi[0][0][n], i1 = cmbi[0][1][n];
        pidx[0][n] = (v1 > v0) ? i1 : i0;
        float u0 = cmbv[1][0][n], u1 = cmbv[1][1][n];
        int   j0 = cmbi[1][0][n], j1 = cmbi[1][1][n];
        pidx[1][n] = (u1 < u0) ? j1 : j0;
    }
    __syncthreads();

    const int partner = pidx[half][n];     // half 0 -> ima, half 1 -> imi

    // ---- Phase B: role 0 computes sim[n][ima], role 1 computes sim[n][imi] ----
    const float* yp = ypred + (size_t)bl * JDIM * NPTS;
    float acc = 0.0f;

    for (int t = 0; t < JDIM / TILE_J; ++t) {
        __syncthreads();                   // previous tile fully consumed
        const float4* src = (const float4*)(yp + (size_t)t * TILE_J * NPTS);
        tiles[tid]        = src[tid];      // 2048 float4, 2 per thread, coalesced
        tiles[1024 + tid] = src[1024 + tid];
        __syncthreads();

        #pragma unroll
        for (int r = 0; r < TILE_J; ++r) {
            float a = smemf[r * NPTS + n];        // stride-1, conflict-free
            float p = smemf[r * NPTS + partner];  // random gather, ~2-way
            acc = fmaf(a, p, acc);
        }
    }

    // signed contribution: sum over block = sum_n (sim@max - sim@min)
    float c = half ? -acc : acc;
    #pragma unroll
    for (int off = 32; off > 0; off >>= 1)
        c += __shfl_down(c, off);
    if ((tid & 63) == 0) wred[tid >> 6] = c;
    __syncthreads();
    if (tid == 0) {
        float s = 0.0f;
        #pragma unroll
        for (int w = 0; w < 16; ++w) s += wred[w];
        partials[bl] = s;
    }
}

__global__ __launch_bounds__(256) void reduce_mean_kernel(
    const float* __restrict__ partials, float* __restrict__ out)
{
    float v = partials[threadIdx.x];
    #pragma unroll
    for (int off = 32; off > 0; off >>= 1)
        v += __shfl_down(v, off);

    __shared__ float w[4];
    if ((threadIdx.x & 63) == 0) w[threadIdx.x >> 6] = v;
    __syncthreads();
    if (threadIdx.x == 0)
        out[0] = (w[0] + w[1] + w[2] + w[3]) * (1.0f / (float)(NBATCH * NPTS));
}

extern "C" void kernel_launch(void* const* d_in, const int* in_sizes, int n_in,
                              void* d_out, int out_size, void* d_ws, size_t ws_size,
                              hipStream_t stream) {
    const float* ypred = (const float*)d_in[0];   // [8,32,128,512] f32
    const float* xyz   = (const float*)d_in[1];   // [8,32,512,3]  f32
    float* partials    = (float*)d_ws;            // 256 floats
    float* out         = (float*)d_out;           // scalar

    fused_loss_kernel<<<NBATCH, 1024, 0, stream>>>(ypred, xyz, partials);
    reduce_mean_kernel<<<1, 256, 0, stream>>>(partials, out);
}

// Round 3
// 124.860 us; speedup vs baseline: 1.2939x; 1.0501x over previous
//
#include <hip/hip_runtime.h>

// Keep the reference's exact fp32 arithmetic for d2: no FMA contraction.
#pragma clang fp contract(off)

#define NBATCH 256   // B*L
#define NPTS   512   // points per batch
#define JDIM   128   // logit dim
#define ROWS_T 8     // ypred rows per tile (8*512*4 = 16 KB), double-buffered
#define NTILE  (JDIM / ROWS_T)   // 16 tiles

// Grid: 512 blocks = 2 per batch; block b -> batch b>>1, point-half b&1.
// Block: 512 threads. Phase A: (sub = tid>>8) scans m-half for point n.
// Phase B: (role = tid>>8) 0 -> sim[n][argmax], 1 -> sim[n][argmin].
__global__ __launch_bounds__(512) void fused_loss_kernel(
    const float* __restrict__ ypred,   // [NBATCH, JDIM, NPTS]
    const float* __restrict__ xyz,     // [NBATCH, NPTS, 3]
    float* __restrict__ partials)      // [2*NBATCH]
{
    __shared__ float tiles[2][ROWS_T * NPTS];   // 32 KB ping-pong (aliases xyz stage)
    __shared__ float maxv[2][256];  __shared__ int maxi[2][256];  // [sub][nl]
    __shared__ float minv[2][256];  __shared__ int mini[2][256];
    __shared__ float wred[8];

    float4* xyzs = (float4*)tiles;     // 512 float4 = 8 KB, phase A only

    const int tid  = threadIdx.x;      // 0..511
    const int nl   = tid & 255;
    const int sub  = tid >> 8;         // phase A: m-half; phase B: role
    const int bl   = blockIdx.x >> 1;
    const int h    = blockIdx.x & 1;   // point-half owned by this block
    const int n    = h * 256 + nl;     // global point id this thread owns

    // ---- stage xyz + squared norms (order matches np.sum(x*x,-1)) ----
    {
        const float* xp = xyz + (size_t)bl * NPTS * 3;
        float x = xp[3 * tid + 0];
        float y = xp[3 * tid + 1];
        float z = xp[3 * tid + 2];
        float sq = (x * x + y * y) + z * z;
        xyzs[tid] = make_float4(x, y, z, sq);
    }
    __syncthreads();

    const float4 pn = xyzs[n];

    // ---- Phase A: scan 256 m's with 2 independent tracks (even/odd) ----
    const int mbase = sub * 256;
    float bmax_e = -1.0f,   bmax_o = -1.0f;   int ima_e = 0, ima_o = 0;
    float bmin_e = 3.0e38f, bmin_o = 3.0e38f; int imi_e = 0, imi_o = 0;

    #pragma unroll 4
    for (int mm = 0; mm < 256; mm += 2) {
        int m = mbase + mm;
        float4 qe = xyzs[m];
        float4 qo = xyzs[m + 1];

        float de = (pn.w + qe.w) - 2.0f * ((pn.x * qe.x + pn.y * qe.y) + pn.z * qe.z);
        de = fmaxf(de, 0.0f);
        float dq = (pn.w + qo.w) - 2.0f * ((pn.x * qo.x + pn.y * qo.y) + pn.z * qo.z);
        dq = fmaxf(dq, 0.0f);

        bool ge = de > bmax_e;  ima_e = ge ? m     : ima_e;  bmax_e = ge ? de : bmax_e;
        bool go = dq > bmax_o;  ima_o = go ? m + 1 : ima_o;  bmax_o = go ? dq : bmax_o;

        float me = (de == 0.0f) ? 1.0e6f : de;   // mask self + exact dupes
        float mo = (dq == 0.0f) ? 1.0e6f : dq;
        bool le = me < bmin_e;  imi_e = le ? m     : imi_e;  bmin_e = le ? me : bmin_e;
        bool lo = mo < bmin_o;  imi_o = lo ? m + 1 : imi_o;  bmin_o = lo ? mo : bmin_o;
    }

    // merge even/odd with first-occurrence tiebreak (value, then lower index)
    {
        bool to = (bmax_o > bmax_e) || (bmax_o == bmax_e && ima_o < ima_e);
        maxv[sub][nl] = to ? bmax_o : bmax_e;
        maxi[sub][nl] = to ? ima_o  : ima_e;
        bool tn = (bmin_o < bmin_e) || (bmin_o == bmin_e && imi_o < imi_e);
        minv[sub][nl] = tn ? bmin_o : bmin_e;
        mini[sub][nl] = tn ? imi_o  : imi_e;
    }
    __syncthreads();

    // merge sub-halves: sub0 indices < sub1 indices, strict compare keeps sub0 on ties
    int partner;
    if (sub == 0) {   // role 0: argmax partner
        partner = (maxv[1][nl] > maxv[0][nl]) ? maxi[1][nl] : maxi[0][nl];
    } else {          // role 1: argmin partner
        partner = (minv[1][nl] < minv[0][nl]) ? mini[1][nl] : mini[0][nl];
    }

    // ---- Phase B: double-buffered ypred tiles, register prefetch ----
    const float* yp = ypred + (size_t)bl * JDIM * NPTS;
    float acc = 0.0f;

    // preload tile 0 (overwrites xyz region; scan reads finished at the sync above)
    {
        const float4* s0 = (const float4*)yp;
        float4 r0 = s0[tid], r1 = s0[512 + tid];
        float4* dst = (float4*)tiles[0];
        dst[tid] = r0;  dst[512 + tid] = r1;
    }
    __syncthreads();

    for (int t = 0; t < NTILE; ++t) {
        float4 p0, p1;
        if (t + 1 < NTILE) {   // issue next tile's global loads before compute
            const float4* sn = (const float4*)(yp + (size_t)(t + 1) * ROWS_T * NPTS);
            p0 = sn[tid];  p1 = sn[512 + tid];
        }

        const float* buf = tiles[t & 1];
        #pragma unroll
        for (int r = 0; r < ROWS_T; ++r) {
            float a = buf[r * NPTS + n];        // stride-1, conflict-free
            float p = buf[r * NPTS + partner];  // random gather, ~2-4 way
            acc = fmaf(a, p, acc);
        }

        if (t + 1 < NTILE) {
            float4* dst = (float4*)tiles[(t + 1) & 1];
            dst[tid] = p0;  dst[512 + tid] = p1;
        }
        __syncthreads();
    }

    // signed contribution: role 0 adds sim@max, role 1 subtracts sim@min
    float c = sub ? -acc : acc;
    #pragma unroll
    for (int off = 32; off > 0; off >>= 1)
        c += __shfl_down(c, off);
    if ((tid & 63) == 0) wred[tid >> 6] = c;
    __syncthreads();
    if (tid == 0) {
        float s = 0.0f;
        #pragma unroll
        for (int w = 0; w < 8; ++w) s += wred[w];
        partials[blockIdx.x] = s;
    }
}

__global__ __launch_bounds__(512) void reduce_mean_kernel(
    const float* __restrict__ partials, float* __restrict__ out)
{
    float v = partials[threadIdx.x];   // 512 partials, 512 threads
    #pragma unroll
    for (int off = 32; off > 0; off >>= 1)
        v += __shfl_down(v, off);

    __shared__ float w[8];
    if ((threadIdx.x & 63) == 0) w[threadIdx.x >> 6] = v;
    __syncthreads();
    if (threadIdx.x == 0) {
        float s = 0.0f;
        #pragma unroll
        for (int i = 0; i < 8; ++i) s += w[i];
        out[0] = s * (1.0f / (float)(NBATCH * NPTS));
    }
}

extern "C" void kernel_launch(void* const* d_in, const int* in_sizes, int n_in,
                              void* d_out, int out_size, void* d_ws, size_t ws_size,
                              hipStream_t stream) {
    const float* ypred = (const float*)d_in[0];   // [8,32,128,512] f32
    const float* xyz   = (const float*)d_in[1];   // [8,32,512,3]  f32
    float* partials    = (float*)d_ws;            // 512 floats
    float* out         = (float*)d_out;           // scalar

    fused_loss_kernel<<<2 * NBATCH, 512, 0, stream>>>(ypred, xyz, partials);
    reduce_mean_kernel<<<1, 512, 0, stream>>>(partials, out);
}